// Round 1
// baseline (133.279 us; speedup 1.0000x reference)
//
#include <hip/hip_runtime.h>

// Problem constants
#define Vn 128
#define Sn 32
#define En 16
#define M0 128
#define Ln 128
#define Bn 16
#define Nn 127
#define BTn 2048
#define RS 20   // padded LDS row stride (dwords) for gather tables

__global__ __launch_bounds__(256, 4) void memnet_main(
    const float* __restrict__ node_fts, const float* __restrict__ edge_fts,
    const float* __restrict__ graph_fts, const float* __restrict__ adjm,
    const float* __restrict__ enc, const float* __restrict__ qb,
    const float* __restrict__ sb, const float* __restrict__ ob,
    const float* __restrict__ mc, const float* __restrict__ wout,
    const float* __restrict__ wfin, float* __restrict__ ret)
{
    __shared__ __align__(16) float sbL[M0 * RS];
    __shared__ __align__(16) float obL[M0 * RS];
    __shared__ __align__(16) float encL[Sn * En];
    __shared__ unsigned int idxw[M0 * 8];       // 32 uint8 idx per slot, packed
    __shared__ float cjT[En * 129];             // Cj transposed, stride 129
    __shared__ float scoresL[M0];
    __shared__ float probsL[M0];
    __shared__ float opart[128];
    __shared__ float uL[En];
    __shared__ float uoL[En];
    __shared__ float xL[Ln];
    __shared__ float red[8];
    // active-slot compaction
    __shared__ int listL[128];
    __shared__ int flagL[128];
    __shared__ int wcnt[2];
    __shared__ float cM[16];   // const mem row for masked slots: sb[0][e]*sum_s enc[s][e]
    __shared__ float cC[16];   // const Cj  row for masked slots: ob[0][e]*sum_s enc[s][e]

    const int t = threadIdx.x;
    const int bt = blockIdx.x;
    const int b = bt >> 7;     // batch
    const int i = bt & 127;    // node row (127 == graph-feature row)

    // ---- stage sb/ob tables (127 rows + zero nil row), padded stride ----
    for (int c = t; c < 512; c += 256) {
        int r = c >> 2, q = c & 3;
        float4 v = make_float4(0.f, 0.f, 0.f, 0.f);
        float4 w = make_float4(0.f, 0.f, 0.f, 0.f);
        if (r < 127) {
            v = *(const float4*)&sb[r * 16 + q * 4];
            w = *(const float4*)&ob[r * 16 + q * 4];
        }
        *(float4*)&sbL[r * RS + q * 4] = v;
        *(float4*)&obL[r * RS + q * 4] = w;
    }
    // ---- stage enc ----
    if (t < 128) {
        *(float4*)&encL[t * 4] = *(const float4*)&enc[t * 4];
    }
    // ---- active flags + ballot-compacted list (slot m = t, t < 128) ----
    if (t < 128) {
        bool flag = false;
        if (i < 127 && t < 127) flag = (adjm[(b * 127 + i) * 127 + t] != 0.f);
        unsigned long long msk = __ballot(flag);
        int lane = t & 63;
        int pos = (int)__popcll(msk & ((1ull << lane) - 1ull));
        if (flag) listL[(t & 64) + pos] = t;       // wave0 -> [0..), wave1 -> [64..)
        if (lane == 0) wcnt[t >> 6] = (int)__popcll(msk);
        flagL[t] = flag ? 1 : 0;
    }
    // ---- build index tile only for active slots: idx = int(edge) ----
    for (int c = t; c < 1024; c += 256) {
        int m = c >> 3, q = c & 7;
        if (i < 127 && m < 127) {
            float a = adjm[(b * 127 + i) * 127 + m];
            if (a != 0.f) {
                const float4 v = *(const float4*)&edge_fts[(size_t)(((b * 127 + i) * 127 + m)) * 32 + q * 4];
                unsigned int packed = (unsigned)(int)v.x | ((unsigned)(int)v.y << 8)
                                    | ((unsigned)(int)v.z << 16) | ((unsigned)(int)v.w << 24);
                idxw[m * 8 + q] = packed;
            }
        }
    }
    // ---- u[e] = sum_s qb[qidx[s]][e] * enc[s][e]; const rows for masked slots ----
    if (t < 16) {
        float ue = 0.f;
        for (int s = 0; s < 32; s++) {
            float qv = (i < 127) ? node_fts[(b * 127 + i) * 32 + s] : graph_fts[b * 32 + s];
            int qi = (int)qv;
            if (qi < 0) qi = 0;
            float w = (qi < 127) ? qb[qi * 16 + t] : 0.f;
            ue = fmaf(w, enc[s * 16 + t], ue);
        }
        uL[t] = ue;
    } else if (t < 32) {
        int e = t - 16;
        float es = 0.f;
        for (int s = 0; s < 32; s++) es += enc[s * 16 + e];
        cM[e] = sb[e] * es;   // sb row 0
        cC[e] = ob[e] * es;   // ob row 0
    }
    __syncthreads();

    // ---- gather phase over COMPACTED active slots ----
    const int eg4 = (t & 3) * 4;
    const int md = t >> 2;          // duo id 0..63
    const int c0 = wcnt[0];
    const int nact = c0 + wcnt[1];
    const int gA = 2 * md;

    if (gA < nact) {
        const int gB = gA + 1;
        const bool actB = (gB < nact);
        int srcA = (gA < c0) ? gA : (gA - c0 + 64);
        int mA = listL[srcA];
        int mB = mA;                                   // dummy duplicate if !actB
        if (actB) {
            int srcB = (gB < c0) ? gB : (gB - c0 + 64);
            mB = listL[srcB];
        }

        float4 aM0 = make_float4(0.f, 0.f, 0.f, 0.f);
        float4 aM1 = make_float4(0.f, 0.f, 0.f, 0.f);
        float4 aC0 = make_float4(0.f, 0.f, 0.f, 0.f);
        float4 aC1 = make_float4(0.f, 0.f, 0.f, 0.f);

        for (int sq = 0; sq < 8; sq++) {
            unsigned w0 = idxw[mA * 8 + sq];
            unsigned w1 = idxw[mB * 8 + sq];
#pragma unroll
            for (int j = 0; j < 4; j++) {
                int s = sq * 4 + j;
                int i0 = (w0 >> (8 * j)) & 0xFF;
                int i1 = (w1 >> (8 * j)) & 0xFF;
                float4 eb = *(const float4*)&encL[s * 16 + eg4];
                float4 a0 = *(const float4*)&sbL[i0 * RS + eg4];
                float4 c0v = *(const float4*)&obL[i0 * RS + eg4];
                float4 a1 = *(const float4*)&sbL[i1 * RS + eg4];
                float4 c1v = *(const float4*)&obL[i1 * RS + eg4];
                aM0.x = fmaf(a0.x, eb.x, aM0.x); aM0.y = fmaf(a0.y, eb.y, aM0.y);
                aM0.z = fmaf(a0.z, eb.z, aM0.z); aM0.w = fmaf(a0.w, eb.w, aM0.w);
                aC0.x = fmaf(c0v.x, eb.x, aC0.x); aC0.y = fmaf(c0v.y, eb.y, aC0.y);
                aC0.z = fmaf(c0v.z, eb.z, aC0.z); aC0.w = fmaf(c0v.w, eb.w, aC0.w);
                aM1.x = fmaf(a1.x, eb.x, aM1.x); aM1.y = fmaf(a1.y, eb.y, aM1.y);
                aM1.z = fmaf(a1.z, eb.z, aM1.z); aM1.w = fmaf(a1.w, eb.w, aM1.w);
                aC1.x = fmaf(c1v.x, eb.x, aC1.x); aC1.y = fmaf(c1v.y, eb.y, aC1.y);
                aC1.z = fmaf(c1v.z, eb.z, aC1.z); aC1.w = fmaf(c1v.w, eb.w, aC1.w);
            }
        }

        // scores: dot(mem + memory_contents, u); Cj -> transposed LDS
        float4 u4 = *(const float4*)&uL[eg4];
        float4 mc0 = *(const float4*)&mc[mA * 16 + eg4];
        float4 mc1 = *(const float4*)&mc[mB * 16 + eg4];
        float p0 = (aM0.x + mc0.x) * u4.x + (aM0.y + mc0.y) * u4.y
                 + (aM0.z + mc0.z) * u4.z + (aM0.w + mc0.w) * u4.w;
        float p1 = (aM1.x + mc1.x) * u4.x + (aM1.y + mc1.y) * u4.y
                 + (aM1.z + mc1.z) * u4.z + (aM1.w + mc1.w) * u4.w;
        p0 += __shfl_xor(p0, 1); p0 += __shfl_xor(p0, 2);
        p1 += __shfl_xor(p1, 1); p1 += __shfl_xor(p1, 2);
        if ((t & 3) == 0) {
            scoresL[mA] = p0;
            if (actB) scoresL[mB] = p1;
        }
        cjT[(eg4 + 0) * 129 + mA] = aC0.x; cjT[(eg4 + 1) * 129 + mA] = aC0.y;
        cjT[(eg4 + 2) * 129 + mA] = aC0.z; cjT[(eg4 + 3) * 129 + mA] = aC0.w;
        if (actB) {
            cjT[(eg4 + 0) * 129 + mB] = aC1.x; cjT[(eg4 + 1) * 129 + mB] = aC1.y;
            cjT[(eg4 + 2) * 129 + mB] = aC1.z; cjT[(eg4 + 3) * 129 + mB] = aC1.w;
        }
    }

    // ---- masked/pad slots: closed-form constant rows ----
    if (t < 128 && !flagL[t]) {
        float p = 0.f;
#pragma unroll
        for (int e4 = 0; e4 < 16; e4 += 4) {
            float4 m4 = *(const float4*)&mc[t * 16 + e4];
            p = fmaf(cM[e4 + 0] + m4.x, uL[e4 + 0], p);
            p = fmaf(cM[e4 + 1] + m4.y, uL[e4 + 1], p);
            p = fmaf(cM[e4 + 2] + m4.z, uL[e4 + 2], p);
            p = fmaf(cM[e4 + 3] + m4.w, uL[e4 + 3], p);
            cjT[(e4 + 0) * 129 + t] = cC[e4 + 0];
            cjT[(e4 + 1) * 129 + t] = cC[e4 + 1];
            cjT[(e4 + 2) * 129 + t] = cC[e4 + 2];
            cjT[(e4 + 3) * 129 + t] = cC[e4 + 3];
        }
        scoresL[t] = p;
    }
    __syncthreads();

    // ---- softmax over 128 slots ----
    {
        float v = (t < 128) ? scoresL[t] : -1e30f;
#pragma unroll
        for (int off = 32; off > 0; off >>= 1) v = fmaxf(v, __shfl_xor(v, off));
        if ((t & 63) == 0) red[t >> 6] = v;
        __syncthreads();
        float mx = fmaxf(fmaxf(red[0], red[1]), fmaxf(red[2], red[3]));
        float ex = (t < 128) ? __expf(scoresL[t] - mx) : 0.f;
        float sv = ex;
#pragma unroll
        for (int off = 32; off > 0; off >>= 1) sv += __shfl_xor(sv, off);
        __syncthreads();
        if ((t & 63) == 0) red[t >> 6] = sv;
        __syncthreads();
        float sum = red[0] + red[1] + red[2] + red[3];
        if (t < 128) probsL[t] = ex / sum;
    }
    __syncthreads();

    // ---- o[e] = sum_m probs[m] * Cj[m][e] ----
    if (t < 128) {
        int e = t & 15, ch = t >> 4;
        float acc = 0.f;
#pragma unroll
        for (int k = 0; k < 16; k++) {
            int m = ch * 16 + k;
            acc = fmaf(probsL[m], cjT[e * 129 + m], acc);
        }
        opart[t] = acc;
    }
    __syncthreads();
    if (t < 16) {
        float o = 0.f;
#pragma unroll
        for (int ch = 0; ch < 8; ch++) o += opart[ch * 16 + t];
        uoL[t] = uL[t] + o;
    }
    __syncthreads();

    // ---- x = relu((u+o) @ W_out) ----
    if (t < 128) {
        float acc = 0.f;
#pragma unroll
        for (int e = 0; e < 16; e++) acc = fmaf(uoL[e], wout[e * 128 + t], acc);
        xL[t] = fmaxf(acc, 0.f);
    }
    __syncthreads();
    // ---- ret = x @ W_fin ----
    if (t < 128) {
        float acc = 0.f;
        for (int l = 0; l < 128; l++) acc = fmaf(xL[l], wfin[l * 128 + t], acc);
        ret[bt * 128 + t] = acc;
    }
}

// out[b,i,v] = ret[b,i,v] + ret[b,127,v]
__global__ void memnet_out(const float* __restrict__ ret, float* __restrict__ out)
{
    int idx = blockIdx.x * 256 + threadIdx.x;
    if (idx >= Bn * Nn * Vn) return;
    int v = idx & 127;
    int r = idx >> 7;          // b*127 + i
    int b = r / 127;
    int i = r - b * 127;
    out[idx] = ret[(b * 128 + i) * 128 + v] + ret[(b * 128 + 127) * 128 + v];
}

extern "C" void kernel_launch(void* const* d_in, const int* in_sizes, int n_in,
                              void* d_out, int out_size, void* d_ws, size_t ws_size,
                              hipStream_t stream)
{
    const float* node  = (const float*)d_in[0];
    const float* edge  = (const float*)d_in[1];
    const float* graph = (const float*)d_in[2];
    const float* adjm  = (const float*)d_in[3];
    // d_in[4] = hidden (unused)
    const float* enc   = (const float*)d_in[5];
    const float* qb    = (const float*)d_in[6];
    const float* sb    = (const float*)d_in[7];
    const float* ob    = (const float*)d_in[8];
    const float* mc    = (const float*)d_in[9];
    // d_in[10] = W_int (unused, num_hops == 1)
    const float* wout  = (const float*)d_in[11];
    const float* wfin  = (const float*)d_in[12];

    float* ws = (float*)d_ws;   // BTn * 128 floats = 1 MB scratch

    memnet_main<<<BTn, 256, 0, stream>>>(node, edge, graph, adjm, enc, qb,
                                         sb, ob, mc, wout, wfin, ws);
    const int total = Bn * Nn * Vn;
    memnet_out<<<(total + 255) / 256, 256, 0, stream>>>(ws, (float*)d_out);
}

// Round 2
// 132.644 us; speedup vs baseline: 1.0048x; 1.0048x over previous
//
#include <hip/hip_runtime.h>

// Problem constants
#define Vn 128
#define Sn 32
#define En 16
#define M0 128
#define Ln 128
#define Bn 16
#define Nn 127
#define NBLK (Bn * Nn)   // 2032 blocks, one per (b, i<127)
#define TRS 36           // combined sb|ob table row stride (dwords)

__global__ __launch_bounds__(256, 5) void memnet_fused(
    const float* __restrict__ node_fts, const float* __restrict__ edge_fts,
    const float* __restrict__ graph_fts, const float* __restrict__ adjm,
    const float* __restrict__ enc, const float* __restrict__ qb,
    const float* __restrict__ sb, const float* __restrict__ ob,
    const float* __restrict__ mc, const float* __restrict__ wout,
    const float* __restrict__ wfin, float* __restrict__ out)
{
    __shared__ __align__(16) float tbl[M0 * TRS];   // [sb(16) | ob(16) | pad(4)] per vocab row
    __shared__ __align__(16) float encL[Sn * En];
    __shared__ unsigned int idxw[M0 * 8];           // 32 uint8 idx per slot, packed
    __shared__ float scoresL[M0];
    __shared__ float probsL[M0];
    __shared__ float uL[En];
    __shared__ float ugL[En];
    __shared__ float uoL[En];
    __shared__ float cM[En];    // sb[0][e] * sum_s enc[s][e]  (masked-slot mem row)
    __shared__ float cC[En];    // ob[0][e] * sum_s enc[s][e]  (masked-slot Cj row)
    __shared__ float xL[Ln];
    __shared__ float xgL[Ln];
    __shared__ float xg2L[Vn];
    __shared__ float owaveL[4 * En];
    __shared__ float red[4], red2[4];
    __shared__ int listL[128];
    __shared__ int flagL[128];
    __shared__ int wcnt[2];

    const int t = threadIdx.x;
    const int bt = blockIdx.x;          // == b*127 + i
    const int b = bt / 127;
    const int lane = t & 63;
    const int wv = t >> 6;

    // ---- stage combined sb|ob table (row 127 = nil zeros) ----
    for (int c = t; c < 1024; c += 256) {
        int r = c >> 3, q = c & 7;
        float4 v = make_float4(0.f, 0.f, 0.f, 0.f);
        if (r < 127)
            v = *(const float4*)((q < 4) ? &sb[r * 16 + q * 4]
                                         : &ob[r * 16 + (q - 4) * 4]);
        *(float4*)&tbl[r * TRS + q * 4] = v;
    }
    // ---- stage enc ----
    if (t < 128) *(float4*)&encL[t * 4] = *(const float4*)&enc[t * 4];

    // ---- active flags + ballot-compacted slot list ----
    if (t < 128) {
        bool flag = (t < 127) && (adjm[(size_t)bt * 127 + t] != 0.f);
        unsigned long long msk = __ballot(flag);
        int pos = (int)__popcll(msk & ((1ull << lane) - 1ull));
        if (flag) listL[(t & 64) + pos] = t;   // wave0 -> [0..), wave1 -> [64..)
        if (lane == 0) wcnt[t >> 6] = (int)__popcll(msk);
        flagL[t] = flag ? 1 : 0;
    }
    // ---- index tile for active slots only ----
    for (int c = t; c < 1024; c += 256) {
        int m = c >> 3, q = c & 7;
        if (m < 127 && adjm[(size_t)bt * 127 + m] != 0.f) {
            float4 v = *(const float4*)&edge_fts[(size_t)(bt * 127 + m) * 32 + q * 4];
            idxw[m * 8 + q] = (unsigned)(int)v.x | ((unsigned)(int)v.y << 8)
                            | ((unsigned)(int)v.z << 16) | ((unsigned)(int)v.w << 24);
        }
    }
    // ---- u (wave0), cM/cC (wave1), u_g graph-row query (wave2) — run in parallel ----
    if (lane < 16) {
        if (wv == 0) {
            float ue = 0.f;
            for (int s = 0; s < 32; s++) {
                int qi = (int)node_fts[(size_t)bt * 32 + s];
                if (qi < 0) qi = 0;
                float w = (qi < 127) ? qb[qi * 16 + lane] : 0.f;
                ue = fmaf(w, enc[s * 16 + lane], ue);
            }
            uL[lane] = ue;
        } else if (wv == 1) {
            float es = 0.f;
            for (int s = 0; s < 32; s++) es += enc[s * 16 + lane];
            cM[lane] = sb[lane] * es;   // vocab row 0
            cC[lane] = ob[lane] * es;
        } else if (wv == 2) {
            float ue = 0.f;
            for (int s = 0; s < 32; s++) {
                int qi = (int)graph_fts[b * 32 + s];
                if (qi < 0) qi = 0;
                float w = (qi < 127) ? qb[qi * 16 + lane] : 0.f;
                ue = fmaf(w, enc[s * 16 + lane], ue);
            }
            ugL[lane] = ue;
        }
    }
    __syncthreads();

    // ---- masked/pad slots: closed-form scores ----
    if (t < 128 && !flagL[t]) {
        float p = 0.f;
#pragma unroll
        for (int e4 = 0; e4 < 16; e4 += 4) {
            float4 m4 = *(const float4*)&mc[t * 16 + e4];
            p = fmaf(cM[e4 + 0] + m4.x, uL[e4 + 0], p);
            p = fmaf(cM[e4 + 1] + m4.y, uL[e4 + 1], p);
            p = fmaf(cM[e4 + 2] + m4.z, uL[e4 + 2], p);
            p = fmaf(cM[e4 + 3] + m4.w, uL[e4 + 3], p);
        }
        scoresL[t] = p;
    }

    // ---- gather: one active slot per quad, all 4 waves ----
    const int eg4 = (t & 3) * 4;
    const int qd = t >> 2;              // quad id 0..63
    const int c0 = wcnt[0];
    const int nact = c0 + wcnt[1];
    const float4 u4 = *(const float4*)&uL[eg4];

    float4 aC_A = make_float4(0.f, 0.f, 0.f, 0.f);
    float4 aC_B = make_float4(0.f, 0.f, 0.f, 0.f);
    int mA = -1, mB = -1;

    if (qd < nact) {
        mA = listL[(qd < c0) ? qd : (qd - c0 + 64)];
        float4 aM = make_float4(0.f, 0.f, 0.f, 0.f);
        for (int sq = 0; sq < 8; sq++) {
            unsigned w0 = idxw[mA * 8 + sq];
#pragma unroll
            for (int j = 0; j < 4; j++) {
                int s = sq * 4 + j;
                int i0 = (w0 >> (8 * j)) & 0xFF;
                float4 eb = *(const float4*)&encL[s * 16 + eg4];
                const float* rp = &tbl[i0 * TRS + eg4];
                float4 a0 = *(const float4*)rp;
                float4 c0v = *(const float4*)(rp + 16);
                aM.x = fmaf(a0.x, eb.x, aM.x); aM.y = fmaf(a0.y, eb.y, aM.y);
                aM.z = fmaf(a0.z, eb.z, aM.z); aM.w = fmaf(a0.w, eb.w, aM.w);
                aC_A.x = fmaf(c0v.x, eb.x, aC_A.x); aC_A.y = fmaf(c0v.y, eb.y, aC_A.y);
                aC_A.z = fmaf(c0v.z, eb.z, aC_A.z); aC_A.w = fmaf(c0v.w, eb.w, aC_A.w);
            }
        }
        float4 mc4 = *(const float4*)&mc[mA * 16 + eg4];
        float p = (aM.x + mc4.x) * u4.x + (aM.y + mc4.y) * u4.y
                + (aM.z + mc4.z) * u4.z + (aM.w + mc4.w) * u4.w;
        p += __shfl_xor(p, 1); p += __shfl_xor(p, 2);
        if ((t & 3) == 0) scoresL[mA] = p;
    }
    if (qd + 64 < nact) {   // rare second pass (nact > 64)
        int g = qd + 64;
        mB = listL[(g < c0) ? g : (g - c0 + 64)];
        float4 aM = make_float4(0.f, 0.f, 0.f, 0.f);
        for (int sq = 0; sq < 8; sq++) {
            unsigned w0 = idxw[mB * 8 + sq];
#pragma unroll
            for (int j = 0; j < 4; j++) {
                int s = sq * 4 + j;
                int i0 = (w0 >> (8 * j)) & 0xFF;
                float4 eb = *(const float4*)&encL[s * 16 + eg4];
                const float* rp = &tbl[i0 * TRS + eg4];
                float4 a0 = *(const float4*)rp;
                float4 c0v = *(const float4*)(rp + 16);
                aM.x = fmaf(a0.x, eb.x, aM.x); aM.y = fmaf(a0.y, eb.y, aM.y);
                aM.z = fmaf(a0.z, eb.z, aM.z); aM.w = fmaf(a0.w, eb.w, aM.w);
                aC_B.x = fmaf(c0v.x, eb.x, aC_B.x); aC_B.y = fmaf(c0v.y, eb.y, aC_B.y);
                aC_B.z = fmaf(c0v.z, eb.z, aC_B.z); aC_B.w = fmaf(c0v.w, eb.w, aC_B.w);
            }
        }
        float4 mc4 = *(const float4*)&mc[mB * 16 + eg4];
        float p = (aM.x + mc4.x) * u4.x + (aM.y + mc4.y) * u4.y
                + (aM.z + mc4.z) * u4.z + (aM.w + mc4.w) * u4.w;
        p += __shfl_xor(p, 1); p += __shfl_xor(p, 2);
        if ((t & 3) == 0) scoresL[mB] = p;
    }
    __syncthreads();

    // ---- softmax over 128 slots (+ masked-prob mass in same reduction) ----
    float pmask;
    {
        float v = (t < 128) ? scoresL[t] : -1e30f;
#pragma unroll
        for (int off = 32; off > 0; off >>= 1) v = fmaxf(v, __shfl_xor(v, off));
        if (lane == 0) red[wv] = v;
        __syncthreads();
        float mx = fmaxf(fmaxf(red[0], red[1]), fmaxf(red[2], red[3]));
        float ex = (t < 128) ? __expf(scoresL[t] - mx) : 0.f;
        float exm = (t < 128 && !flagL[t]) ? ex : 0.f;
        float sv = ex, sm = exm;
#pragma unroll
        for (int off = 32; off > 0; off >>= 1) {
            sv += __shfl_xor(sv, off);
            sm += __shfl_xor(sm, off);
        }
        __syncthreads();
        if (lane == 0) { red[wv] = sv; red2[wv] = sm; }
        __syncthreads();
        float sum = red[0] + red[1] + red[2] + red[3];
        pmask = (red2[0] + red2[1] + red2[2] + red2[3]) / sum;
        if (t < 128) probsL[t] = ex / sum;
    }
    __syncthreads();

    // ---- o_active: probs-weighted Cj from registers, shfl-tree reduce ----
    {
        float4 op = make_float4(0.f, 0.f, 0.f, 0.f);
        if (mA >= 0) {
            float pa = probsL[mA];
            op.x = pa * aC_A.x; op.y = pa * aC_A.y;
            op.z = pa * aC_A.z; op.w = pa * aC_A.w;
        }
        if (mB >= 0) {
            float pb = probsL[mB];
            op.x = fmaf(pb, aC_B.x, op.x); op.y = fmaf(pb, aC_B.y, op.y);
            op.z = fmaf(pb, aC_B.z, op.z); op.w = fmaf(pb, aC_B.w, op.w);
        }
#pragma unroll
        for (int off = 4; off <= 32; off <<= 1) {
            op.x += __shfl_xor(op.x, off);
            op.y += __shfl_xor(op.y, off);
            op.z += __shfl_xor(op.z, off);
            op.w += __shfl_xor(op.w, off);
        }
        if (lane < 4) *(float4*)&owaveL[wv * 16 + lane * 4] = op;
    }
    __syncthreads();
    if (t < 16) {
        float o = owaveL[t] + owaveL[16 + t] + owaveL[32 + t] + owaveL[48 + t];
        uoL[t] = uL[t] + o + cC[t] * pmask;   // masked slots contribute cC * (their prob mass)
    }
    __syncthreads();

    // ---- x = relu(uo @ W_out); xg = relu((u_g + cC) @ W_out) in the other half ----
    if (t < 128) {
        float acc = 0.f;
#pragma unroll
        for (int e = 0; e < 16; e++) acc = fmaf(uoL[e], wout[e * 128 + t], acc);
        xL[t] = fmaxf(acc, 0.f);
    } else {
        int l = t - 128;
        float acc = 0.f;
#pragma unroll
        for (int e = 0; e < 16; e++) acc = fmaf(ugL[e] + cC[e], wout[e * 128 + l], acc);
        xgL[l] = fmaxf(acc, 0.f);
    }
    __syncthreads();

    // ---- ret = x @ W_fin (half 0) ; ret127 = xg @ W_fin (half 1); out = sum ----
    {
        const int vcol = t & 127;
        const float* xsrc = (t < 128) ? xL : xgL;   // wave-uniform base
        float acc = 0.f;
        for (int l = 0; l < 128; l++) acc = fmaf(xsrc[l], wfin[l * 128 + vcol], acc);
        if (t >= 128) xg2L[vcol] = acc;
        __syncthreads();
        if (t < 128) out[(size_t)bt * 128 + vcol] = acc + xg2L[vcol];
    }
}

extern "C" void kernel_launch(void* const* d_in, const int* in_sizes, int n_in,
                              void* d_out, int out_size, void* d_ws, size_t ws_size,
                              hipStream_t stream)
{
    const float* node  = (const float*)d_in[0];
    const float* edge  = (const float*)d_in[1];
    const float* graph = (const float*)d_in[2];
    const float* adjm  = (const float*)d_in[3];
    // d_in[4] = hidden (unused)
    const float* enc   = (const float*)d_in[5];
    const float* qb    = (const float*)d_in[6];
    const float* sb    = (const float*)d_in[7];
    const float* ob    = (const float*)d_in[8];
    const float* mc    = (const float*)d_in[9];
    // d_in[10] = W_int (unused, num_hops == 1)
    const float* wout  = (const float*)d_in[11];
    const float* wfin  = (const float*)d_in[12];

    memnet_fused<<<NBLK, 256, 0, stream>>>(node, edge, graph, adjm, enc, qb,
                                           sb, ob, mc, wout, wfin, (float*)d_out);
}